// Round 6
// baseline (1591.956 us; speedup 1.0000x reference)
//
#include <hip/hip_runtime.h>

#define NN 32768   // nodes
#define NB 256     // graphs
#define HD 128     // hidden
#define NL 4       // layers
#define NE 262144  // edges

typedef short bf16x8 __attribute__((ext_vector_type(8)));
typedef float f32x4 __attribute__((ext_vector_type(4)));
typedef unsigned short u16;
typedef unsigned int u32;

__device__ __forceinline__ float bf2f(u16 u) {
  return __uint_as_float(((u32)u) << 16);
}
__device__ __forceinline__ u16 f2bf(float f) {
  u32 x = __float_as_uint(f);
  u32 r = x + 0x7FFFu + ((x >> 16) & 1u);
  return (u16)(r >> 16);
}
__device__ __forceinline__ u32 pk2(float a, float b) {
  return (u32)f2bf(a) | ((u32)f2bf(b) << 16);
}
__device__ __forceinline__ float siluf(float x) {
  return x * __builtin_amdgcn_rcpf(1.0f + __expf(-x));
}
__device__ __forceinline__ float sigf(float x) {
  return __builtin_amdgcn_rcpf(1.0f + __expf(-x));
}
__device__ __forceinline__ u32 ordu(float f) {
  u32 b = __float_as_uint(f);
  return (b & 0x80000000u) ? ~b : (b | 0x80000000u);
}

// ---- adaptive input loads: mode 1 = f32 inputs, mode 0 = bf16 inputs ----
__device__ __forceinline__ float ldinf(const void* p, size_t i, int mode) {
  return mode ? ((const float*)p)[i] : bf2f(((const u16*)p)[i]);
}
__device__ __forceinline__ u16 ldinb(const void* p, size_t i, int mode) {
  return mode ? f2bf(((const float*)p)[i]) : ((const u16*)p)[i];
}

// ---- dtype detector (confirmed mode=1/f32; kept as cheap guard) ----
__global__ void k_detect(const u16* __restrict__ Weraw, int* __restrict__ flag) {
  if (threadIdx.x == 0 && blockIdx.x == 0) {
    int cnt = 0;
    for (int i = 0; i < 256; i++) {
      u16 u = Weraw[2 * i];
      u32 e = (u >> 7) & 0xFFu;
      if (e >= 112u && e <= 126u) cnt++;
    }
    *flag = (cnt >= 128) ? 0 : 1;
  }
}

// ---------------- CSR build (by dst), reused across all 4 layers ----------------
__global__ __launch_bounds__(256) void k_csr_deg(const int* __restrict__ dstp,
                                                 u32* __restrict__ deg) {
  const int i = blockIdx.x * 256 + threadIdx.x;
  atomicAdd(&deg[dstp[i]], 1u);
}

__global__ __launch_bounds__(1024) void k_csr_scan(const u32* __restrict__ deg,
                                                   int* __restrict__ rowptr,
                                                   int* __restrict__ cursor) {
  __shared__ int part[1024];
  const int t = threadIdx.x;
  int loc[32];
  int s = 0;
#pragma unroll
  for (int j = 0; j < 32; j++) { loc[j] = s; s += (int)deg[t * 32 + j]; }
  part[t] = s;
  __syncthreads();
  int inc = s;
  for (int off = 1; off < 1024; off <<= 1) {
    int tmp = (t >= off) ? part[t - off] : 0;
    __syncthreads();
    part[t] += tmp;
    __syncthreads();
  }
  const int base = part[t] - inc;  // exclusive prefix of this thread's chunk
#pragma unroll
  for (int j = 0; j < 32; j++) {
    rowptr[t * 32 + j] = base + loc[j];
    cursor[t * 32 + j] = base + loc[j];
  }
  if (t == 1023) rowptr[NN] = part[1023];
}

__global__ __launch_bounds__(256) void k_csr_scatter(const int* __restrict__ dstp,
                                                     int* __restrict__ cursor,
                                                     int* __restrict__ eids) {
  const int i = blockIdx.x * 256 + threadIdx.x;
  const int pos = atomicAdd(&cursor[dstp[i]], 1);
  eids[pos] = i;
}

// ---------------- per-wave GEMM pieces ----------------
// Wave tile: 64 rows x 128 cols, mfma_f32_16x16x32_bf16.
// A-frag: lane l holds A[row=(l&15)+16*mt][k=(l>>4)*8+j]  (16B contiguous)
// C/D: col = lane&15, row = (lane>>4)*4 + reg  (m89-verified)
// LDS tile: [64 rows][128 shorts], XOR-swizzled 16B granules:
//   granule_lds = granule_logical ^ (row & 7)
// Packed k_new order: granule g element j <-> h = j*16 + g
//   => lane l's h=l value: short offset r*HD + ((l&15)^(r&7))*8 + (l>>4); h=l+64 at +4.

__device__ __forceinline__ void acc_zero(f32x4 (&acc)[4][8]) {
#pragma unroll
  for (int mt = 0; mt < 4; mt++)
#pragma unroll
    for (int nt = 0; nt < 8; nt++) acc[mt][nt] = f32x4{0.f, 0.f, 0.f, 0.f};
}

// GEMM with A-fragments loaded DIRECTLY from global rows (no LDS staging).
template <int BSTRIDE>
__device__ __forceinline__ void gemm_g(const u16* __restrict__ A0,
                                       const size_t* rowoff,
                                       const u16* __restrict__ Bp,
                                       int c, int kg, f32x4 (&acc)[4][8]) {
#pragma unroll
  for (int ks = 0; ks < 4; ks++) {
    bf16x8 a[4];
#pragma unroll
    for (int mt = 0; mt < 4; mt++)
      a[mt] = *(const bf16x8*)&A0[rowoff[mt] + ks * 32 + kg * 8];
#pragma unroll
    for (int nt = 0; nt < 8; nt++) {
      bf16x8 b = *(const bf16x8*)&Bp[(nt * 16 + c) * BSTRIDE + ks * 32 + kg * 8];
#pragma unroll
      for (int mt = 0; mt < 4; mt++)
        acc[mt][nt] = __builtin_amdgcn_mfma_f32_16x16x32_bf16(a[mt], b, acc[mt][nt], 0, 0, 0);
    }
  }
}

// GEMM with A from swizzled LDS tile
template <int KSTEPS, int BSTRIDE>
__device__ __forceinline__ void wave_gemm(const short* lAw, const u16* Bp,
                                          int c, int kg, f32x4 (&acc)[4][8]) {
#pragma unroll
  for (int ks = 0; ks < KSTEPS; ks++) {
    bf16x8 a[4];
#pragma unroll
    for (int mt = 0; mt < 4; mt++) {
      const int r = mt * 16 + c;
      const int k = ks * 32 + kg * 8;
      a[mt] = *(const bf16x8*)&lAw[r * HD + (k ^ ((r & 7) << 3))];
    }
#pragma unroll
    for (int nt = 0; nt < 8; nt++) {
      bf16x8 b = *(const bf16x8*)&Bp[(nt * 16 + c) * BSTRIDE + ks * 32 + kg * 8];
#pragma unroll
      for (int mt = 0; mt < 4; mt++)
        acc[mt][nt] = __builtin_amdgcn_mfma_f32_16x16x32_bf16(a[mt], b, acc[mt][nt], 0, 0, 0);
    }
  }
}

template <bool SILU>
__device__ __forceinline__ void wave_pack(short* lAw, int c, int kg,
                                          f32x4 (&acc)[4][8], const float* bias) {
#pragma unroll
  for (int mt = 0; mt < 4; mt++) {
#pragma unroll
    for (int rr = 0; rr < 4; rr++) {
      const int row = mt * 16 + kg * 4 + rr;
      u32 ou[4];
#pragma unroll
      for (int p = 0; p < 4; p++) {
        float x0 = acc[mt][2 * p][rr] + bias[2 * p];
        float x1 = acc[mt][2 * p + 1][rr] + bias[2 * p + 1];
        if (SILU) { x0 = siluf(x0); x1 = siluf(x1); }
        ou[p] = pk2(x0, x1);
      }
      ((int4*)(lAw + row * HD))[c ^ (row & 7)] =
          make_int4((int)ou[0], (int)ou[1], (int)ou[2], (int)ou[3]);
    }
  }
}

// ---------------- weight prep ----------------
__global__ __launch_bounds__(256) void k_prep(
    const void* __restrict__ mW1, const void* __restrict__ mW2,
    const void* __restrict__ uW1, const void* __restrict__ uW2,
    const void* __restrict__ oW1, const void* __restrict__ oW2,
    const int* __restrict__ flagp,
    u16* __restrict__ Wt1, u16* __restrict__ Wt2p,
    u16* __restrict__ Wtu1, u16* __restrict__ Wtu2p,
    u16* __restrict__ Wto1, u16* __restrict__ Wto2p) {
  const int mode = *flagp;
  const int tid = blockIdx.x * blockDim.x + threadIdx.x;
  const int stride = gridDim.x * blockDim.x;
  for (int i = tid; i < NL * HD * 384; i += stride) {
    int l = i / (HD * 384), r = i % (HD * 384), n = r / 384, k = r % 384;
    Wt1[i] = ldinb(mW1, ((size_t)l * 384 + k) * HD + n, mode);
  }
  for (int i = tid; i < NL * HD * HD; i += stride) {
    int l = i / (HD * HD), r = i % (HD * HD), n = r / HD, k = r % HD;
    int h = ((k & 7) << 4) | (k >> 3);
    Wt2p[i] = ldinb(mW2, ((size_t)l * HD + h) * HD + n, mode);
    Wtu1[i] = ldinb(uW1, ((size_t)l * HD + k) * HD + n, mode);
    Wtu2p[i] = ldinb(uW2, ((size_t)l * HD + h) * HD + n, mode);
  }
  for (int i = tid; i < HD * HD; i += stride) {
    int n = i / HD, k = i % HD;
    int h = ((k & 7) << 4) | (k >> 3);
    Wto1[i] = ldinb(oW1, (size_t)k * HD + n, mode);
    Wto2p[i] = ldinb(oW2, (size_t)h * HD + n, mode);
  }
}

// ---------------- feat init ----------------
__global__ __launch_bounds__(256) void k_featinit(const void* __restrict__ nemb,
                                                  const int* __restrict__ flagp,
                                                  u16* __restrict__ feat) {
  const int mode = *flagp;
  const int i = blockIdx.x * 256 + threadIdx.x;
  const int g = i & 15;
  u32 ou[4];
#pragma unroll
  for (int p = 0; p < 4; p++) {
    u16 a = ldinb(nemb, g * 8 + 2 * p, mode);
    u16 b = ldinb(nemb, g * 8 + 2 * p + 1, mode);
    ou[p] = (u32)a | ((u32)b << 16);
  }
  ((int4*)feat)[i] = make_int4((int)ou[0], (int)ou[1], (int)ou[2], (int)ou[3]);
}

// ---------------- edge feature encode ----------------
__global__ __launch_bounds__(256) void k_encode(const void* __restrict__ d,
                                                const void* __restrict__ We,
                                                const void* __restrict__ be,
                                                const int* __restrict__ flagp,
                                                u16* __restrict__ e) {
  const int mode = *flagp;
  __shared__ float sW[9 * HD];
  __shared__ float sb[HD];
  for (int i = threadIdx.x; i < 9 * HD; i += 256) sW[i] = ldinf(We, i, mode);
  for (int i = threadIdx.x; i < HD; i += 256) sb[i] = ldinf(be, i, mode);
  __syncthreads();
  const int eid = blockIdx.x * 256 + threadIdx.x;
  const float dv = ldinf(d, eid, mode);
  float de[9];
#pragma unroll
  for (int k = 0; k < 4; k++) {
    float x = dv * (1.0f / (float)(1 << k));
    de[k] = __sinf(x);
    de[4 + k] = __cosf(x);
  }
  de[8] = dv;
  u16* erow = e + (size_t)eid * HD;
#pragma unroll
  for (int hb = 0; hb < 16; hb++) {
    u32 ou[4];
#pragma unroll
    for (int p = 0; p < 4; p++) {
      float vv[2];
#pragma unroll
      for (int t = 0; t < 2; t++) {
        const int h = hb * 8 + 2 * p + t;
        float a = sb[h];
#pragma unroll
        for (int k = 0; k < 9; k++) a += de[k] * sW[k * HD + h];
        vv[t] = siluf(siluf(a));
      }
      ou[p] = pk2(vv[0], vv[1]);
    }
    ((int4*)erow)[hb] = make_int4((int)ou[0], (int)ou[1], (int)ou[2], (int)ou[3]);
  }
}

// ---------------- edge message layer (the heavy kernel) ----------------
// GEMM1 A-frags direct from global; LDS only for h1 -> GEMM2 -> m round trip.
// Epilogue: NO atomics — store m rows (mbuf) + gate (wgbuf) + e residual RMW,
// all coalesced plain memory ops. Aggregation happens in k_node via CSR.
__global__ __launch_bounds__(64, 2) void k_edge(
    const u16* __restrict__ feat, u16* __restrict__ e,
    const int* __restrict__ src, const int* __restrict__ dstp,
    const u16* __restrict__ Wt1, const u16* __restrict__ Wt2p,
    const void* __restrict__ b1g, const void* __restrict__ b2g,
    const void* __restrict__ softW, const void* __restrict__ softb,
    const int* __restrict__ flagp, u32* __restrict__ mbuf32,
    float* __restrict__ wgbuf, int layer) {
  __shared__ __align__(16) short lM[64 * HD];
  __shared__ float swg[64];
  const int mode = *flagp;
  const int l = threadIdx.x;
  const int c = l & 15, kg = l >> 4;
  const int blk = blockIdx.x * 64;

  // fragment row offsets (shorts) for the 3 GEMM1 sources
  size_t offS[4], offD[4], offE[4];
#pragma unroll
  for (int mt = 0; mt < 4; mt++) {
    const int eidx = blk + mt * 16 + c;
    offS[mt] = (size_t)src[eidx] * HD;
    offD[mt] = (size_t)dstp[eidx] * HD;
    offE[mt] = (size_t)eidx * HD;
  }

  const u16* W1l = Wt1 + (size_t)layer * HD * 384;
  const u16* W2l = Wt2p + (size_t)layer * HD * HD;
  float bias1[8], bias2[8], swf[8];
#pragma unroll
  for (int nt = 0; nt < 8; nt++) {
    bias1[nt] = ldinf(b1g, layer * HD + nt * 16 + c, mode);
    bias2[nt] = ldinf(b2g, layer * HD + nt * 16 + c, mode);
    swf[nt] = ldinf(softW, (size_t)layer * HD + nt * 16 + c, mode);
  }
  const float sb = ldinf(softb, layer, mode);

  f32x4 acc[4][8];
  acc_zero(acc);
  // GEMM1: mi = [feat[src] | feat[dst] | e] @ W1
  gemm_g<384>(feat, offS, W1l, c, kg, acc);
  gemm_g<384>(feat, offD, W1l + 128, c, kg, acc);
  gemm_g<384>(e, offE, W1l + 256, c, kg, acc);
  wave_pack<true>(lM, c, kg, acc, bias1);   // h1 = silu(. + b1), k_new order
  __syncthreads();

  acc_zero(acc);
  wave_gemm<4, HD>(lM, W2l, c, kg, acc);    // h1 @ W2 (k-permuted weights)
  __syncthreads();

  // ---- fused pack + soft-gate ----
  float wred[4][4];
#pragma unroll
  for (int mt = 0; mt < 4; mt++) {
#pragma unroll
    for (int rr = 0; rr < 4; rr++) {
      const int row = mt * 16 + kg * 4 + rr;
      float mv[8];
      float wp = 0.f;
#pragma unroll
      for (int nt = 0; nt < 8; nt++) {
        mv[nt] = siluf(acc[mt][nt][rr] + bias2[nt]);
        wp += mv[nt] * swf[nt];
      }
      u32 ou[4];
#pragma unroll
      for (int p = 0; p < 4; p++) ou[p] = pk2(mv[2 * p], mv[2 * p + 1]);
      ((int4*)(lM + row * HD))[c ^ (row & 7)] =
          make_int4((int)ou[0], (int)ou[1], (int)ou[2], (int)ou[3]);
      wp += __shfl_xor(wp, 1);
      wp += __shfl_xor(wp, 2);
      wp += __shfl_xor(wp, 4);
      wp += __shfl_xor(wp, 8);
      wred[mt][rr] = wp;
    }
  }
#pragma unroll
  for (int mt = 0; mt < 4; mt++)
#pragma unroll
    for (int rr = 0; rr < 4; rr++)
      if (c == mt * 4 + rr) swg[mt * 16 + kg * 4 + rr] = sigf(wred[mt][rr] + sb);
  __syncthreads();

  wgbuf[blk + l] = swg[l];

  // ---- cooperative per-row: mbuf store + e residual RMW (coalesced, no atomics)
  const int j1 = l >> 4;
  const int goff = l & 15;
  const bool hilane = (l >= 32);
  const int s0 = (2 * l) & 63, s1 = (2 * l + 1) & 63;
#pragma unroll 4
  for (int r = 0; r < 64; r++) {
    const int base = r * HD + ((goff ^ (r & 7)) << 3) + j1;
    const u32 m1 = (u16)lM[base];        // h = l
    const u32 m2 = (u16)lM[base + 4];    // h = l + 64
    const u32 pk = m1 | (m2 << 16);
    const u32 a = (u32)__shfl((int)pk, s0);
    const u32 b = (u32)__shfl((int)pk, s1);
    const u32 lo = hilane ? (a >> 16) : (a & 0xffffu);
    const u32 hi = hilane ? (b >> 16) : (b & 0xffffu);
    mbuf32[(size_t)(blk + r) * 64 + l] = lo | (hi << 16);   // m at h=2l,2l+1
    u32* erow32 = (u32*)(e + (size_t)(blk + r) * HD);
    const u32 old = erow32[l];
    erow32[l] = pk2(bf2f((u16)(old & 0xffffu)) + bf2f((u16)lo),
                    bf2f((u16)(old >> 16)) + bf2f((u16)hi));
  }
}

// ---------------- node update layer (CSR gather, no atomics) ----------------
__global__ __launch_bounds__(64, 2) void k_node(
    u16* __restrict__ feat,
    const int* __restrict__ rowptr, const int* __restrict__ eids,
    const u32* __restrict__ mbuf32, const float* __restrict__ wgbuf,
    const u16* __restrict__ Wtu1, const u16* __restrict__ Wtu2p,
    const void* __restrict__ b1g, const void* __restrict__ b2g,
    const int* __restrict__ flagp, int layer) {
  __shared__ __align__(16) short lA[64 * HD];
  const int mode = *flagp;
  const int l = threadIdx.x;
  const int c = l & 15, kg = l >> 4;
  short* lAw = lA;
  const int blkn = blockIdx.x * 64;
  const u16* W1l = Wtu1 + (size_t)layer * HD * HD;
  const u16* W2l = Wtu2p + (size_t)layer * HD * HD;
  float bias1[8], bias2[8];
#pragma unroll
  for (int nt = 0; nt < 8; nt++) {
    bias1[nt] = ldinf(b1g, layer * HD + nt * 16 + c, mode);
    bias2[nt] = ldinf(b2g, layer * HD + nt * 16 + c, mode);
  }

  // stage upd_in = feat + sum_{CSR edges} wg[e] * m[e]  (lane l owns h=2l,2l+1)
  for (int r = 0; r < 64; r++) {
    const int node = blkn + r;
    const int beg = rowptr[node];
    const int end = rowptr[node + 1];
    float a0 = 0.f, a1 = 0.f;
    for (int cb = beg; cb < end; cb += 64) {
      const int nj = min(64, end - cb);
      int eL = 0;
      float wL = 0.f;
      if (cb + l < end) { eL = eids[cb + l]; wL = wgbuf[eL]; }
      for (int j = 0; j < nj; j++) {
        const int eid = __shfl(eL, j);
        const float w = __shfl(wL, j);
        const u32 v = mbuf32[(size_t)eid * 64 + l];
        a0 += w * bf2f((u16)(v & 0xffffu));
        a1 += w * bf2f((u16)(v >> 16));
      }
    }
    const u32 f = ((const u32*)(feat + (size_t)node * HD))[l];
    a0 += bf2f((u16)(f & 0xffffu));
    a1 += bf2f((u16)(f >> 16));
    *(u32*)(lAw + r * HD + (((l >> 2) ^ (r & 7)) << 3) + ((2 * l) & 7)) = pk2(a0, a1);
  }
  __syncthreads();

  f32x4 acc[4][8];
  acc_zero(acc);
  wave_gemm<4, HD>(lAw, W1l, c, kg, acc);
  __syncthreads();
  wave_pack<true>(lAw, c, kg, acc, bias1);
  __syncthreads();
  acc_zero(acc);
  wave_gemm<4, HD>(lAw, W2l, c, kg, acc);
  __syncthreads();
  wave_pack<false>(lAw, c, kg, acc, bias2);
  __syncthreads();

  // cooperative feat residual: coalesced u32 RMW per row
  const int j1 = l >> 4;
  const int goff = l & 15;
  const bool hilane = (l >= 32);
  const int s0 = (2 * l) & 63, s1 = (2 * l + 1) & 63;
#pragma unroll 4
  for (int r = 0; r < 64; r++) {
    const int base = r * HD + ((goff ^ (r & 7)) << 3) + j1;
    const u32 m1 = (u16)lAw[base];
    const u32 m2 = (u16)lAw[base + 4];
    const u32 pk = m1 | (m2 << 16);
    const u32 a = (u32)__shfl((int)pk, s0);
    const u32 b = (u32)__shfl((int)pk, s1);
    const u32 lo = hilane ? (a >> 16) : (a & 0xffffu);
    const u32 hi = hilane ? (b >> 16) : (b & 0xffffu);
    u32* frow32 = (u32*)(feat + (size_t)(blkn + r) * HD);
    const u32 old = frow32[l];
    frow32[l] = pk2(bf2f((u16)(old & 0xffffu)) + bf2f((u16)lo),
                    bf2f((u16)(old >> 16)) + bf2f((u16)hi));
  }
}

// ---------------- output MLP + readout ----------------
__global__ __launch_bounds__(64, 2) void k_out(
    const u16* __restrict__ feat, const int* __restrict__ seg,
    const u16* __restrict__ Wto1, const u16* __restrict__ Wto2p,
    const void* __restrict__ ob1, const void* __restrict__ ob2,
    const int* __restrict__ flagp,
    float* __restrict__ sacc, u32* __restrict__ mxacc, float* __restrict__ cnt) {
  __shared__ __align__(16) short lA[64 * HD];
  __shared__ int sseg[64];
  const int mode = *flagp;
  const int l = threadIdx.x;
  const int c = l & 15, kg = l >> 4;
  short* lAw = lA;
  const int myrow = blockIdx.x * 64 + l;
  const u16* frow = feat + (size_t)myrow * HD;
  float bias1[8], bias2[8];
#pragma unroll
  for (int nt = 0; nt < 8; nt++) {
    bias1[nt] = ldinf(ob1, nt * 16 + c, mode);
    bias2[nt] = ldinf(ob2, nt * 16 + c, mode);
  }
  {
    int4* lrow = (int4*)(lAw + l * HD);
#pragma unroll
    for (int g = 0; g < 16; g++) lrow[g ^ (l & 7)] = ((const int4*)frow)[g];
  }
  sseg[l] = seg[myrow];
  __syncthreads();
  f32x4 acc[4][8];
  acc_zero(acc);
  wave_gemm<4, HD>(lAw, Wto1, c, kg, acc);
  __syncthreads();
  wave_pack<true>(lAw, c, kg, acc, bias1);
  __syncthreads();
  acc_zero(acc);
  wave_gemm<4, HD>(lAw, Wto2p, c, kg, acc);
  __syncthreads();
  wave_pack<false>(lAw, c, kg, acc, bias2);
  __syncthreads();

  const int j1 = l >> 4;
  const int goff = l & 15;
  const bool uniform = (sseg[0] == sseg[63]);
  if (uniform) {
    const int g = sseg[0];
    float s1 = 0.f, s2 = 0.f, x1 = -3.402823e38f, x2 = -3.402823e38f;
#pragma unroll 4
    for (int r = 0; r < 64; r++) {
      const int base = r * HD + ((goff ^ (r & 7)) << 3) + j1;
      const float v1 = bf2f((u16)lAw[base]);
      const float v2 = bf2f((u16)lAw[base + 4]);
      s1 += v1; s2 += v2;
      x1 = fmaxf(x1, v1); x2 = fmaxf(x2, v2);
    }
    atomicAdd(&sacc[(size_t)g * HD + l], s1);
    atomicAdd(&sacc[(size_t)g * HD + l + 64], s2);
    atomicMax(&mxacc[(size_t)g * HD + l], ordu(x1));
    atomicMax(&mxacc[(size_t)g * HD + l + 64], ordu(x2));
    if (l == 0) atomicAdd(&cnt[g], 64.0f);
  } else {
    atomicAdd(&cnt[sseg[l]], 1.0f);
#pragma unroll 4
    for (int r = 0; r < 64; r++) {
      const int base = r * HD + ((goff ^ (r & 7)) << 3) + j1;
      const float v1 = bf2f((u16)lAw[base]);
      const float v2 = bf2f((u16)lAw[base + 4]);
      const int g = sseg[r];
      atomicAdd(&sacc[(size_t)g * HD + l], v1);
      atomicAdd(&sacc[(size_t)g * HD + l + 64], v2);
      atomicMax(&mxacc[(size_t)g * HD + l], ordu(v1));
      atomicMax(&mxacc[(size_t)g * HD + l + 64], ordu(v2));
    }
  }
}

// ---------------- finalize ----------------
__global__ __launch_bounds__(256) void k_final(const float* __restrict__ sacc,
                                               const u32* __restrict__ mxacc,
                                               const float* __restrict__ cnt,
                                               const int* __restrict__ flagp,
                                               void* __restrict__ out) {
  const int mode = *flagp;
  const int i = blockIdx.x * 256 + threadIdx.x;
  const int b = i / 384, j = i % 384;
  float v;
  if (j < HD) v = sacc[b * HD + j];
  else if (j < 2 * HD) v = sacc[b * HD + (j - HD)] / fmaxf(cnt[b], 1.0f);
  else {
    u32 u = mxacc[b * HD + (j - 2 * HD)];
    u32 bits = (u >> 31) ? (u ^ 0x80000000u) : ~u;
    v = __uint_as_float(bits);
  }
  if (mode) ((float*)out)[i] = v;
  else ((u16*)out)[i] = f2bf(v);
}

extern "C" void kernel_launch(void* const* d_in, const int* in_sizes, int n_in,
                              void* d_out, int out_size, void* d_ws, size_t ws_size,
                              hipStream_t stream) {
  const void* d_d = d_in[0];
  const int* src = (const int*)d_in[1];
  const int* dst = (const int*)d_in[2];
  const int* seg = (const int*)d_in[3];
  const void* nemb = d_in[4];
  const void* We = d_in[5];
  const void* be = d_in[6];
  const void* mW1 = d_in[7];
  const void* mb1 = d_in[8];
  const void* mW2 = d_in[9];
  const void* mb2 = d_in[10];
  const void* sW = d_in[11];
  const void* sb = d_in[12];
  const void* uW1 = d_in[13];
  const void* ub1 = d_in[14];
  const void* uW2 = d_in[15];
  const void* ub2 = d_in[16];
  const void* oW1 = d_in[17];
  const void* ob1 = d_in[18];
  const void* oW2 = d_in[19];
  const void* ob2 = d_in[20];

  char* ws = (char*)d_ws;
  const size_t OFF_E = 0;
  const size_t OFF_MBUF = OFF_E + (size_t)NE * HD * 2;
  const size_t OFF_WG = OFF_MBUF + (size_t)NE * HD * 2;
  const size_t OFF_FEAT = OFF_WG + (size_t)NE * 4;
  const size_t OFF_SACC = OFF_FEAT + (size_t)NN * HD * 2;
  const size_t OFF_MX = OFF_SACC + (size_t)NB * HD * 4;
  const size_t OFF_CNT = OFF_MX + (size_t)NB * HD * 4;
  const size_t OFF_DEG = OFF_CNT + 1024;               // u32[NN]
  const size_t OFF_ROWPTR = OFF_DEG + (size_t)NN * 4;  // int[NN+1] (+pad)
  const size_t OFF_CURSOR = OFF_ROWPTR + (size_t)(NN + 2) * 4;
  const size_t OFF_EIDS = OFF_CURSOR + (size_t)NN * 4;
  const size_t OFF_WT1 = OFF_EIDS + (size_t)NE * 4;
  const size_t OFF_WT2P = OFF_WT1 + (size_t)NL * HD * 384 * 2;
  const size_t OFF_WTU1 = OFF_WT2P + (size_t)NL * HD * HD * 2;
  const size_t OFF_WTU2P = OFF_WTU1 + (size_t)NL * HD * HD * 2;
  const size_t OFF_WTO1 = OFF_WTU2P + (size_t)NL * HD * HD * 2;
  const size_t OFF_WTO2P = OFF_WTO1 + (size_t)HD * HD * 2;
  const size_t OFF_FLAG = OFF_WTO2P + (size_t)HD * HD * 2;

  u16* e = (u16*)(ws + OFF_E);
  u32* mbuf32 = (u32*)(ws + OFF_MBUF);
  float* wgbuf = (float*)(ws + OFF_WG);
  u16* feat = (u16*)(ws + OFF_FEAT);
  float* sacc = (float*)(ws + OFF_SACC);
  u32* mx = (u32*)(ws + OFF_MX);
  float* cnt = (float*)(ws + OFF_CNT);
  u32* deg = (u32*)(ws + OFF_DEG);
  int* rowptr = (int*)(ws + OFF_ROWPTR);
  int* cursor = (int*)(ws + OFF_CURSOR);
  int* eids = (int*)(ws + OFF_EIDS);
  u16* Wt1 = (u16*)(ws + OFF_WT1);
  u16* Wt2p = (u16*)(ws + OFF_WT2P);
  u16* Wtu1 = (u16*)(ws + OFF_WTU1);
  u16* Wtu2p = (u16*)(ws + OFF_WTU2P);
  u16* Wto1 = (u16*)(ws + OFF_WTO1);
  u16* Wto2p = (u16*)(ws + OFF_WTO2P);
  int* flag = (int*)(ws + OFF_FLAG);

  // zero sacc + mx + cnt + deg (contiguous region)
  hipMemsetAsync(ws + OFF_SACC, 0,
                 (size_t)NB * HD * 4 * 2 + 1024 + (size_t)NN * 4, stream);

  k_detect<<<1, 64, 0, stream>>>((const u16*)We, flag);
  k_prep<<<256, 256, 0, stream>>>(mW1, mW2, uW1, uW2, oW1, oW2, flag,
                                  Wt1, Wt2p, Wtu1, Wtu2p, Wto1, Wto2p);
  k_featinit<<<(NN * HD / 8) / 256, 256, 0, stream>>>(nemb, flag, feat);
  k_encode<<<NE / 256, 256, 0, stream>>>(d_d, We, be, flag, e);

  // CSR by dst (reused across layers)
  k_csr_deg<<<NE / 256, 256, 0, stream>>>(dst, deg);
  k_csr_scan<<<1, 1024, 0, stream>>>(deg, rowptr, cursor);
  k_csr_scatter<<<NE / 256, 256, 0, stream>>>(dst, cursor, eids);

  for (int l = 0; l < NL; l++) {
    k_edge<<<NE / 64, 64, 0, stream>>>(feat, e, src, dst, Wt1, Wt2p,
                                       mb1, mb2, sW, sb, flag, mbuf32, wgbuf, l);
    k_node<<<NN / 64, 64, 0, stream>>>(feat, rowptr, eids, mbuf32, wgbuf,
                                       Wtu1, Wtu2p, ub1, ub2, flag, l);
  }
  k_out<<<NN / 64, 64, 0, stream>>>(feat, seg, Wto1, Wto2p, ob1, ob2, flag, sacc, mx, cnt);
  k_final<<<(NB * 384) / 256, 256, 0, stream>>>(sacc, mx, cnt, flag, d_out);
}

// Round 7
// 1084.094 us; speedup vs baseline: 1.4685x; 1.4685x over previous
//
#include <hip/hip_runtime.h>

#define NN 32768   // nodes
#define NB 256     // graphs
#define HD 128     // hidden
#define NL 4       // layers
#define NE 262144  // edges

typedef short bf16x8 __attribute__((ext_vector_type(8)));
typedef float f32x4 __attribute__((ext_vector_type(4)));
typedef unsigned short u16;
typedef unsigned int u32;

__device__ __forceinline__ float bf2f(u16 u) {
  return __uint_as_float(((u32)u) << 16);
}
__device__ __forceinline__ u16 f2bf(float f) {
  u32 x = __float_as_uint(f);
  u32 r = x + 0x7FFFu + ((x >> 16) & 1u);
  return (u16)(r >> 16);
}
__device__ __forceinline__ u32 pk2(float a, float b) {
  return (u32)f2bf(a) | ((u32)f2bf(b) << 16);
}
__device__ __forceinline__ float siluf(float x) {
  return x * __builtin_amdgcn_rcpf(1.0f + __expf(-x));
}
__device__ __forceinline__ float sigf(float x) {
  return __builtin_amdgcn_rcpf(1.0f + __expf(-x));
}
__device__ __forceinline__ u32 ordu(float f) {
  u32 b = __float_as_uint(f);
  return (b & 0x80000000u) ? ~b : (b | 0x80000000u);
}

// ---- adaptive input loads: mode 1 = f32 inputs, mode 0 = bf16 inputs ----
__device__ __forceinline__ float ldinf(const void* p, size_t i, int mode) {
  return mode ? ((const float*)p)[i] : bf2f(((const u16*)p)[i]);
}
__device__ __forceinline__ u16 ldinb(const void* p, size_t i, int mode) {
  return mode ? f2bf(((const float*)p)[i]) : ((const u16*)p)[i];
}

// ---- dtype detector (confirmed mode=1/f32; kept as cheap guard) ----
__global__ void k_detect(const u16* __restrict__ Weraw, int* __restrict__ flag) {
  if (threadIdx.x == 0 && blockIdx.x == 0) {
    int cnt = 0;
    for (int i = 0; i < 256; i++) {
      u16 u = Weraw[2 * i];
      u32 e = (u >> 7) & 0xFFu;
      if (e >= 112u && e <= 126u) cnt++;
    }
    *flag = (cnt >= 128) ? 0 : 1;
  }
}

// ---------------- CSR build (by dst), reused across all 4 layers ----------------
__global__ __launch_bounds__(256) void k_csr_deg(const int* __restrict__ dstp,
                                                 u32* __restrict__ deg) {
  const int i = blockIdx.x * 256 + threadIdx.x;
  atomicAdd(&deg[dstp[i]], 1u);
}

__global__ __launch_bounds__(1024) void k_csr_scan(const u32* __restrict__ deg,
                                                   int* __restrict__ rowptr,
                                                   int* __restrict__ cursor) {
  __shared__ int part[1024];
  const int t = threadIdx.x;
  int loc[32];
  int s = 0;
#pragma unroll
  for (int j = 0; j < 32; j++) { loc[j] = s; s += (int)deg[t * 32 + j]; }
  part[t] = s;
  __syncthreads();
  int inc = s;
  for (int off = 1; off < 1024; off <<= 1) {
    int tmp = (t >= off) ? part[t - off] : 0;
    __syncthreads();
    part[t] += tmp;
    __syncthreads();
  }
  const int base = part[t] - inc;
#pragma unroll
  for (int j = 0; j < 32; j++) {
    rowptr[t * 32 + j] = base + loc[j];
    cursor[t * 32 + j] = base + loc[j];
  }
  if (t == 1023) rowptr[NN] = part[1023];
}

__global__ __launch_bounds__(256) void k_csr_scatter(const int* __restrict__ dstp,
                                                     int* __restrict__ cursor,
                                                     int* __restrict__ eids) {
  const int i = blockIdx.x * 256 + threadIdx.x;
  const int pos = atomicAdd(&cursor[dstp[i]], 1);
  eids[pos] = i;
}

// ---------------- per-wave GEMM pieces (templated on MT = rows/16) -------------
// Wave tile: MT*16 rows x 128 cols, mfma_f32_16x16x32_bf16.
// A-frag: lane l holds A[row=(l&15)+16*mt][k=(l>>4)*8+j]  (16B contiguous)
// C/D: col = lane&15, row = (lane>>4)*4 + reg  (m89-verified)
// LDS tile: [MT*16 rows][128 shorts], XOR-swizzled 16B granules:
//   granule_lds = granule_logical ^ (row & 7)
// Packed k_new order: granule g element j <-> h = j*16 + g
//   => lane l's h=l value: short offset r*HD + ((l&15)^(r&7))*8 + (l>>4); h=l+64 at +4.

template <int MT>
__device__ __forceinline__ void acc_zero(f32x4 (&acc)[MT][8]) {
#pragma unroll
  for (int mt = 0; mt < MT; mt++)
#pragma unroll
    for (int nt = 0; nt < 8; nt++) acc[mt][nt] = f32x4{0.f, 0.f, 0.f, 0.f};
}

// GEMM with A-fragments loaded DIRECTLY from global rows (no LDS staging).
template <int MT, int BSTRIDE>
__device__ __forceinline__ void gemm_g(const u16* __restrict__ A0,
                                       const size_t* rowoff,
                                       const u16* __restrict__ Bp,
                                       int c, int kg, f32x4 (&acc)[MT][8]) {
#pragma unroll
  for (int ks = 0; ks < 4; ks++) {
    bf16x8 a[MT];
#pragma unroll
    for (int mt = 0; mt < MT; mt++)
      a[mt] = *(const bf16x8*)&A0[rowoff[mt] + ks * 32 + kg * 8];
#pragma unroll
    for (int nt = 0; nt < 8; nt++) {
      bf16x8 b = *(const bf16x8*)&Bp[(nt * 16 + c) * BSTRIDE + ks * 32 + kg * 8];
#pragma unroll
      for (int mt = 0; mt < MT; mt++)
        acc[mt][nt] = __builtin_amdgcn_mfma_f32_16x16x32_bf16(a[mt], b, acc[mt][nt], 0, 0, 0);
    }
  }
}

// GEMM with A from swizzled LDS tile
template <int MT, int BSTRIDE>
__device__ __forceinline__ void wave_gemm(const short* lAw, const u16* Bp,
                                          int c, int kg, f32x4 (&acc)[MT][8]) {
#pragma unroll
  for (int ks = 0; ks < 4; ks++) {
    bf16x8 a[MT];
#pragma unroll
    for (int mt = 0; mt < MT; mt++) {
      const int r = mt * 16 + c;
      const int k = ks * 32 + kg * 8;
      a[mt] = *(const bf16x8*)&lAw[r * HD + (k ^ ((r & 7) << 3))];
    }
#pragma unroll
    for (int nt = 0; nt < 8; nt++) {
      bf16x8 b = *(const bf16x8*)&Bp[(nt * 16 + c) * BSTRIDE + ks * 32 + kg * 8];
#pragma unroll
      for (int mt = 0; mt < MT; mt++)
        acc[mt][nt] = __builtin_amdgcn_mfma_f32_16x16x32_bf16(a[mt], b, acc[mt][nt], 0, 0, 0);
    }
  }
}

template <int MT, bool SILU>
__device__ __forceinline__ void wave_pack(short* lAw, int c, int kg,
                                          f32x4 (&acc)[MT][8], const float* bias) {
#pragma unroll
  for (int mt = 0; mt < MT; mt++) {
#pragma unroll
    for (int rr = 0; rr < 4; rr++) {
      const int row = mt * 16 + kg * 4 + rr;
      u32 ou[4];
#pragma unroll
      for (int p = 0; p < 4; p++) {
        float x0 = acc[mt][2 * p][rr] + bias[2 * p];
        float x1 = acc[mt][2 * p + 1][rr] + bias[2 * p + 1];
        if (SILU) { x0 = siluf(x0); x1 = siluf(x1); }
        ou[p] = pk2(x0, x1);
      }
      ((int4*)(lAw + row * HD))[c ^ (row & 7)] =
          make_int4((int)ou[0], (int)ou[1], (int)ou[2], (int)ou[3]);
    }
  }
}

// ---------------- weight prep ----------------
__global__ __launch_bounds__(256) void k_prep(
    const void* __restrict__ mW1, const void* __restrict__ mW2,
    const void* __restrict__ uW1, const void* __restrict__ uW2,
    const void* __restrict__ oW1, const void* __restrict__ oW2,
    const int* __restrict__ flagp,
    u16* __restrict__ Wt1, u16* __restrict__ Wt2p,
    u16* __restrict__ Wtu1, u16* __restrict__ Wtu2p,
    u16* __restrict__ Wto1, u16* __restrict__ Wto2p) {
  const int mode = *flagp;
  const int tid = blockIdx.x * blockDim.x + threadIdx.x;
  const int stride = gridDim.x * blockDim.x;
  for (int i = tid; i < NL * HD * 384; i += stride) {
    int l = i / (HD * 384), r = i % (HD * 384), n = r / 384, k = r % 384;
    Wt1[i] = ldinb(mW1, ((size_t)l * 384 + k) * HD + n, mode);
  }
  for (int i = tid; i < NL * HD * HD; i += stride) {
    int l = i / (HD * HD), r = i % (HD * HD), n = r / HD, k = r % HD;
    int h = ((k & 7) << 4) | (k >> 3);
    Wt2p[i] = ldinb(mW2, ((size_t)l * HD + h) * HD + n, mode);
    Wtu1[i] = ldinb(uW1, ((size_t)l * HD + k) * HD + n, mode);
    Wtu2p[i] = ldinb(uW2, ((size_t)l * HD + h) * HD + n, mode);
  }
  for (int i = tid; i < HD * HD; i += stride) {
    int n = i / HD, k = i % HD;
    int h = ((k & 7) << 4) | (k >> 3);
    Wto1[i] = ldinb(oW1, (size_t)k * HD + n, mode);
    Wto2p[i] = ldinb(oW2, (size_t)h * HD + n, mode);
  }
}

// ---------------- feat init ----------------
__global__ __launch_bounds__(256) void k_featinit(const void* __restrict__ nemb,
                                                  const int* __restrict__ flagp,
                                                  u16* __restrict__ feat) {
  const int mode = *flagp;
  const int i = blockIdx.x * 256 + threadIdx.x;
  const int g = i & 15;
  u32 ou[4];
#pragma unroll
  for (int p = 0; p < 4; p++) {
    u16 a = ldinb(nemb, g * 8 + 2 * p, mode);
    u16 b = ldinb(nemb, g * 8 + 2 * p + 1, mode);
    ou[p] = (u32)a | ((u32)b << 16);
  }
  ((int4*)feat)[i] = make_int4((int)ou[0], (int)ou[1], (int)ou[2], (int)ou[3]);
}

// ---------------- edge feature encode ----------------
__global__ __launch_bounds__(256) void k_encode(const void* __restrict__ d,
                                                const void* __restrict__ We,
                                                const void* __restrict__ be,
                                                const int* __restrict__ flagp,
                                                u16* __restrict__ e) {
  const int mode = *flagp;
  __shared__ float sW[9 * HD];
  __shared__ float sb[HD];
  for (int i = threadIdx.x; i < 9 * HD; i += 256) sW[i] = ldinf(We, i, mode);
  for (int i = threadIdx.x; i < HD; i += 256) sb[i] = ldinf(be, i, mode);
  __syncthreads();
  const int eid = blockIdx.x * 256 + threadIdx.x;
  const float dv = ldinf(d, eid, mode);
  float de[9];
#pragma unroll
  for (int k = 0; k < 4; k++) {
    float x = dv * (1.0f / (float)(1 << k));
    de[k] = __sinf(x);
    de[4 + k] = __cosf(x);
  }
  de[8] = dv;
  u16* erow = e + (size_t)eid * HD;
#pragma unroll
  for (int hb = 0; hb < 16; hb++) {
    u32 ou[4];
#pragma unroll
    for (int p = 0; p < 4; p++) {
      float vv[2];
#pragma unroll
      for (int t = 0; t < 2; t++) {
        const int h = hb * 8 + 2 * p + t;
        float a = sb[h];
#pragma unroll
        for (int k = 0; k < 9; k++) a += de[k] * sW[k * HD + h];
        vv[t] = siluf(siluf(a));
      }
      ou[p] = pk2(vv[0], vv[1]);
    }
    ((int4*)erow)[hb] = make_int4((int)ou[0], (int)ou[1], (int)ou[2], (int)ou[3]);
  }
}

// ---------------- edge message layer: M=32 tiles for occupancy ----------------
// GEMM1 A-frags direct from global; LDS (8.2KB) only for h1 -> GEMM2 -> m.
// No atomics: mbuf/wgbuf stores + e residual RMW, all coalesced.
__global__ __launch_bounds__(64, 4) void k_edge(
    const u16* __restrict__ feat, u16* __restrict__ e,
    const int* __restrict__ src, const int* __restrict__ dstp,
    const u16* __restrict__ Wt1, const u16* __restrict__ Wt2p,
    const void* __restrict__ b1g, const void* __restrict__ b2g,
    const void* __restrict__ softW, const void* __restrict__ softb,
    const int* __restrict__ flagp, u32* __restrict__ mbuf32,
    float* __restrict__ wgbuf, int layer) {
  __shared__ __align__(16) short lM[32 * HD];
  __shared__ float swg[32];
  const int mode = *flagp;
  const int l = threadIdx.x;
  const int c = l & 15, kg = l >> 4;
  const int blk = blockIdx.x * 32;

  size_t offS[2], offD[2], offE[2];
#pragma unroll
  for (int mt = 0; mt < 2; mt++) {
    const int eidx = blk + mt * 16 + c;
    offS[mt] = (size_t)src[eidx] * HD;
    offD[mt] = (size_t)dstp[eidx] * HD;
    offE[mt] = (size_t)eidx * HD;
  }

  const u16* W1l = Wt1 + (size_t)layer * HD * 384;
  const u16* W2l = Wt2p + (size_t)layer * HD * HD;
  float bias1[8], bias2[8], swf[8];
#pragma unroll
  for (int nt = 0; nt < 8; nt++) {
    bias1[nt] = ldinf(b1g, layer * HD + nt * 16 + c, mode);
    bias2[nt] = ldinf(b2g, layer * HD + nt * 16 + c, mode);
    swf[nt] = ldinf(softW, (size_t)layer * HD + nt * 16 + c, mode);
  }
  const float sbv = ldinf(softb, layer, mode);

  f32x4 acc[2][8];
  acc_zero<2>(acc);
  gemm_g<2, 384>(feat, offS, W1l, c, kg, acc);
  gemm_g<2, 384>(feat, offD, W1l + 128, c, kg, acc);
  gemm_g<2, 384>(e, offE, W1l + 256, c, kg, acc);
  wave_pack<2, true>(lM, c, kg, acc, bias1);   // h1, k_new order
  __syncthreads();

  acc_zero<2>(acc);
  wave_gemm<2, HD>(lM, W2l, c, kg, acc);       // h1 @ W2 (k-permuted)
  __syncthreads();

  // ---- fused pack + soft-gate ----
  float wred[2][4];
#pragma unroll
  for (int mt = 0; mt < 2; mt++) {
#pragma unroll
    for (int rr = 0; rr < 4; rr++) {
      const int row = mt * 16 + kg * 4 + rr;
      float mv[8];
      float wp = 0.f;
#pragma unroll
      for (int nt = 0; nt < 8; nt++) {
        mv[nt] = siluf(acc[mt][nt][rr] + bias2[nt]);
        wp += mv[nt] * swf[nt];
      }
      u32 ou[4];
#pragma unroll
      for (int p = 0; p < 4; p++) ou[p] = pk2(mv[2 * p], mv[2 * p + 1]);
      ((int4*)(lM + row * HD))[c ^ (row & 7)] =
          make_int4((int)ou[0], (int)ou[1], (int)ou[2], (int)ou[3]);
      wp += __shfl_xor(wp, 1);
      wp += __shfl_xor(wp, 2);
      wp += __shfl_xor(wp, 4);
      wp += __shfl_xor(wp, 8);
      wred[mt][rr] = wp;
    }
  }
#pragma unroll
  for (int mt = 0; mt < 2; mt++)
#pragma unroll
    for (int rr = 0; rr < 4; rr++)
      if (c == mt * 4 + rr) swg[mt * 16 + kg * 4 + rr] = sigf(wred[mt][rr] + sbv);
  __syncthreads();

  if (l < 32) wgbuf[blk + l] = swg[l];

  // ---- cooperative per-row: mbuf store + e residual RMW ----
  const int j1 = l >> 4;
  const int goff = l & 15;
  const bool hilane = (l >= 32);
  const int s0 = (2 * l) & 63, s1 = (2 * l + 1) & 63;
#pragma unroll 4
  for (int r = 0; r < 32; r++) {
    const int base = r * HD + ((goff ^ (r & 7)) << 3) + j1;
    const u32 m1 = (u16)lM[base];        // h = l
    const u32 m2 = (u16)lM[base + 4];    // h = l + 64
    const u32 pk = m1 | (m2 << 16);
    const u32 a = (u32)__shfl((int)pk, s0);
    const u32 b = (u32)__shfl((int)pk, s1);
    const u32 lo = hilane ? (a >> 16) : (a & 0xffffu);
    const u32 hi = hilane ? (b >> 16) : (b & 0xffffu);
    mbuf32[(size_t)(blk + r) * 64 + l] = lo | (hi << 16);   // m at h=2l,2l+1
    u32* erow32 = (u32*)(e + (size_t)(blk + r) * HD);
    const u32 old = erow32[l];
    erow32[l] = pk2(bf2f((u16)(old & 0xffffu)) + bf2f((u16)lo),
                    bf2f((u16)(old >> 16)) + bf2f((u16)hi));
  }
}

// ---------------- msum gather: one wave per node (massively parallel) ---------
__global__ __launch_bounds__(256) void k_gather(
    const int* __restrict__ rowptr, const int* __restrict__ eids,
    const u32* __restrict__ mbuf32, const float* __restrict__ wgbuf,
    float* __restrict__ msum) {
  const int w = threadIdx.x >> 6;
  const int l = threadIdx.x & 63;
  const int node = blockIdx.x * 4 + w;
  const int beg = rowptr[node], end = rowptr[node + 1];
  float a0 = 0.f, a1 = 0.f;
  for (int cb = beg; cb < end; cb += 64) {
    int eL = 0;
    float wL = 0.f;
    if (cb + l < end) { eL = eids[cb + l]; wL = wgbuf[eL]; }
    const int nj = min(64, end - cb);
    for (int j = 0; j < nj; j++) {
      const int eid = __shfl(eL, j);
      const float wj = __shfl(wL, j);
      const u32 v = mbuf32[(size_t)eid * 64 + l];
      a0 += wj * bf2f((u16)(v & 0xffffu));
      a1 += wj * bf2f((u16)(v >> 16));
    }
  }
  ((float2*)(msum + (size_t)node * HD))[l] = make_float2(a0, a1);  // h=2l,2l+1
}

// ---------------- node update layer (reads msum, round-5 structure) -----------
__global__ __launch_bounds__(64, 2) void k_node(
    u16* __restrict__ feat, const float* __restrict__ msum,
    const u16* __restrict__ Wtu1, const u16* __restrict__ Wtu2p,
    const void* __restrict__ b1g, const void* __restrict__ b2g,
    const int* __restrict__ flagp, int layer) {
  __shared__ __align__(16) short lA[64 * HD];
  const int mode = *flagp;
  const int l = threadIdx.x;
  const int c = l & 15, kg = l >> 4;
  short* lAw = lA;
  const int blkn = blockIdx.x * 64;
  const int myrow = blkn + l;
  u16* frow = feat + (size_t)myrow * HD;
  const float* mrow = msum + (size_t)myrow * HD;
  const u16* W1l = Wtu1 + (size_t)layer * HD * HD;
  const u16* W2l = Wtu2p + (size_t)layer * HD * HD;
  float bias1[8], bias2[8];
#pragma unroll
  for (int nt = 0; nt < 8; nt++) {
    bias1[nt] = ldinf(b1g, layer * HD + nt * 16 + c, mode);
    bias2[nt] = ldinf(b2g, layer * HD + nt * 16 + c, mode);
  }
  {
    int4* lrow = (int4*)(lAw + l * HD);
#pragma unroll
    for (int g = 0; g < 16; g++) {
      int4 fv = ((const int4*)frow)[g];
      u32 uu[4] = {(u32)fv.x, (u32)fv.y, (u32)fv.z, (u32)fv.w};
      float4 ma = ((const float4*)mrow)[2 * g];
      float4 mb = ((const float4*)mrow)[2 * g + 1];
      float mm[8] = {ma.x, ma.y, ma.z, ma.w, mb.x, mb.y, mb.z, mb.w};
      u32 ou[4];
#pragma unroll
      for (int p = 0; p < 4; p++) {
        float a0 = bf2f((u16)(uu[p] & 0xffffu)) + mm[2 * p];
        float a1 = bf2f((u16)(uu[p] >> 16)) + mm[2 * p + 1];
        ou[p] = pk2(a0, a1);
      }
      lrow[g ^ (l & 7)] = make_int4((int)ou[0], (int)ou[1], (int)ou[2], (int)ou[3]);
    }
  }
  __syncthreads();
  f32x4 acc[4][8];
  acc_zero<4>(acc);
  wave_gemm<4, HD>(lAw, W1l, c, kg, acc);
  __syncthreads();
  wave_pack<4, true>(lAw, c, kg, acc, bias1);
  __syncthreads();
  acc_zero<4>(acc);
  wave_gemm<4, HD>(lAw, W2l, c, kg, acc);
  __syncthreads();
  wave_pack<4, false>(lAw, c, kg, acc, bias2);
  __syncthreads();

  // cooperative feat residual: coalesced u32 RMW per row
  const int j1 = l >> 4;
  const int goff = l & 15;
  const bool hilane = (l >= 32);
  const int s0 = (2 * l) & 63, s1 = (2 * l + 1) & 63;
#pragma unroll 4
  for (int r = 0; r < 64; r++) {
    const int base = r * HD + ((goff ^ (r & 7)) << 3) + j1;
    const u32 m1 = (u16)lAw[base];
    const u32 m2 = (u16)lAw[base + 4];
    const u32 pk = m1 | (m2 << 16);
    const u32 a = (u32)__shfl((int)pk, s0);
    const u32 b = (u32)__shfl((int)pk, s1);
    const u32 lo = hilane ? (a >> 16) : (a & 0xffffu);
    const u32 hi = hilane ? (b >> 16) : (b & 0xffffu);
    u32* frow32 = (u32*)(feat + (size_t)(blkn + r) * HD);
    const u32 old = frow32[l];
    frow32[l] = pk2(bf2f((u16)(old & 0xffffu)) + bf2f((u16)lo),
                    bf2f((u16)(old >> 16)) + bf2f((u16)hi));
  }
}

// ---------------- output MLP + readout ----------------
__global__ __launch_bounds__(64, 2) void k_out(
    const u16* __restrict__ feat, const int* __restrict__ seg,
    const u16* __restrict__ Wto1, const u16* __restrict__ Wto2p,
    const void* __restrict__ ob1, const void* __restrict__ ob2,
    const int* __restrict__ flagp,
    float* __restrict__ sacc, u32* __restrict__ mxacc, float* __restrict__ cnt) {
  __shared__ __align__(16) short lA[64 * HD];
  __shared__ int sseg[64];
  const int mode = *flagp;
  const int l = threadIdx.x;
  const int c = l & 15, kg = l >> 4;
  short* lAw = lA;
  const int myrow = blockIdx.x * 64 + l;
  const u16* frow = feat + (size_t)myrow * HD;
  float bias1[8], bias2[8];
#pragma unroll
  for (int nt = 0; nt < 8; nt++) {
    bias1[nt] = ldinf(ob1, nt * 16 + c, mode);
    bias2[nt] = ldinf(ob2, nt * 16 + c, mode);
  }
  {
    int4* lrow = (int4*)(lAw + l * HD);
#pragma unroll
    for (int g = 0; g < 16; g++) lrow[g ^ (l & 7)] = ((const int4*)frow)[g];
  }
  sseg[l] = seg[myrow];
  __syncthreads();
  f32x4 acc[4][8];
  acc_zero<4>(acc);
  wave_gemm<4, HD>(lAw, Wto1, c, kg, acc);
  __syncthreads();
  wave_pack<4, true>(lAw, c, kg, acc, bias1);
  __syncthreads();
  acc_zero<4>(acc);
  wave_gemm<4, HD>(lAw, Wto2p, c, kg, acc);
  __syncthreads();
  wave_pack<4, false>(lAw, c, kg, acc, bias2);
  __syncthreads();

  const int j1 = l >> 4;
  const int goff = l & 15;
  const bool uniform = (sseg[0] == sseg[63]);
  if (uniform) {
    const int g = sseg[0];
    float s1 = 0.f, s2 = 0.f, x1 = -3.402823e38f, x2 = -3.402823e38f;
#pragma unroll 4
    for (int r = 0; r < 64; r++) {
      const int base = r * HD + ((goff ^ (r & 7)) << 3) + j1;
      const float v1 = bf2f((u16)lAw[base]);
      const float v2 = bf2f((u16)lAw[base + 4]);
      s1 += v1; s2 += v2;
      x1 = fmaxf(x1, v1); x2 = fmaxf(x2, v2);
    }
    atomicAdd(&sacc[(size_t)g * HD + l], s1);
    atomicAdd(&sacc[(size_t)g * HD + l + 64], s2);
    atomicMax(&mxacc[(size_t)g * HD + l], ordu(x1));
    atomicMax(&mxacc[(size_t)g * HD + l + 64], ordu(x2));
    if (l == 0) atomicAdd(&cnt[g], 64.0f);
  } else {
    atomicAdd(&cnt[sseg[l]], 1.0f);
#pragma unroll 4
    for (int r = 0; r < 64; r++) {
      const int base = r * HD + ((goff ^ (r & 7)) << 3) + j1;
      const float v1 = bf2f((u16)lAw[base]);
      const float v2 = bf2f((u16)lAw[base + 4]);
      const int g = sseg[r];
      atomicAdd(&sacc[(size_t)g * HD + l], v1);
      atomicAdd(&sacc[(size_t)g * HD + l + 64], v2);
      atomicMax(&mxacc[(size_t)g * HD + l], ordu(v1));
      atomicMax(&mxacc[(size_t)g * HD + l + 64], ordu(v2));
    }
  }
}

// ---------------- finalize ----------------
__global__ __launch_bounds__(256) void k_final(const float* __restrict__ sacc,
                                               const u32* __restrict__ mxacc,
                                               const float* __restrict__ cnt,
                                               const int* __restrict__ flagp,
                                               void* __restrict__ out) {
  const int mode = *flagp;
  const int i = blockIdx.x * 256 + threadIdx.x;
  const int b = i / 384, j = i % 384;
  float v;
  if (j < HD) v = sacc[b * HD + j];
  else if (j < 2 * HD) v = sacc[b * HD + (j - HD)] / fmaxf(cnt[b], 1.0f);
  else {
    u32 u = mxacc[b * HD + (j - 2 * HD)];
    u32 bits = (u >> 31) ? (u ^ 0x80000000u) : ~u;
    v = __uint_as_float(bits);
  }
  if (mode) ((float*)out)[i] = v;
  else ((u16*)out)[i] = f2bf(v);
}

extern "C" void kernel_launch(void* const* d_in, const int* in_sizes, int n_in,
                              void* d_out, int out_size, void* d_ws, size_t ws_size,
                              hipStream_t stream) {
  const void* d_d = d_in[0];
  const int* src = (const int*)d_in[1];
  const int* dst = (const int*)d_in[2];
  const int* seg = (const int*)d_in[3];
  const void* nemb = d_in[4];
  const void* We = d_in[5];
  const void* be = d_in[6];
  const void* mW1 = d_in[7];
  const void* mb1 = d_in[8];
  const void* mW2 = d_in[9];
  const void* mb2 = d_in[10];
  const void* sW = d_in[11];
  const void* sb = d_in[12];
  const void* uW1 = d_in[13];
  const void* ub1 = d_in[14];
  const void* uW2 = d_in[15];
  const void* ub2 = d_in[16];
  const void* oW1 = d_in[17];
  const void* ob1 = d_in[18];
  const void* oW2 = d_in[19];
  const void* ob2 = d_in[20];

  char* ws = (char*)d_ws;
  const size_t OFF_E = 0;
  const size_t OFF_MBUF = OFF_E + (size_t)NE * HD * 2;
  const size_t OFF_WG = OFF_MBUF + (size_t)NE * HD * 2;
  const size_t OFF_MSUM = OFF_WG + (size_t)NE * 4;
  const size_t OFF_FEAT = OFF_MSUM + (size_t)NN * HD * 4;
  const size_t OFF_SACC = OFF_FEAT + (size_t)NN * HD * 2;
  const size_t OFF_MX = OFF_SACC + (size_t)NB * HD * 4;
  const size_t OFF_CNT = OFF_MX + (size_t)NB * HD * 4;
  const size_t OFF_DEG = OFF_CNT + 1024;
  const size_t OFF_ROWPTR = OFF_DEG + (size_t)NN * 4;
  const size_t OFF_CURSOR = OFF_ROWPTR + (size_t)(NN + 2) * 4;
  const size_t OFF_EIDS = OFF_CURSOR + (size_t)NN * 4;
  const size_t OFF_WT1 = OFF_EIDS + (size_t)NE * 4;
  const size_t OFF_WT2P = OFF_WT1 + (size_t)NL * HD * 384 * 2;
  const size_t OFF_WTU1 = OFF_WT2P + (size_t)NL * HD * HD * 2;
  const size_t OFF_WTU2P = OFF_WTU1 + (size_t)NL * HD * HD * 2;
  const size_t OFF_WTO1 = OFF_WTU2P + (size_t)NL * HD * HD * 2;
  const size_t OFF_WTO2P = OFF_WTO1 + (size_t)HD * HD * 2;
  const size_t OFF_FLAG = OFF_WTO2P + (size_t)HD * HD * 2;

  u16* e = (u16*)(ws + OFF_E);
  u32* mbuf32 = (u32*)(ws + OFF_MBUF);
  float* wgbuf = (float*)(ws + OFF_WG);
  float* msum = (float*)(ws + OFF_MSUM);
  u16* feat = (u16*)(ws + OFF_FEAT);
  float* sacc = (float*)(ws + OFF_SACC);
  u32* mx = (u32*)(ws + OFF_MX);
  float* cnt = (float*)(ws + OFF_CNT);
  u32* deg = (u32*)(ws + OFF_DEG);
  int* rowptr = (int*)(ws + OFF_ROWPTR);
  int* cursor = (int*)(ws + OFF_CURSOR);
  int* eids = (int*)(ws + OFF_EIDS);
  u16* Wt1 = (u16*)(ws + OFF_WT1);
  u16* Wt2p = (u16*)(ws + OFF_WT2P);
  u16* Wtu1 = (u16*)(ws + OFF_WTU1);
  u16* Wtu2p = (u16*)(ws + OFF_WTU2P);
  u16* Wto1 = (u16*)(ws + OFF_WTO1);
  u16* Wto2p = (u16*)(ws + OFF_WTO2P);
  int* flag = (int*)(ws + OFF_FLAG);

  // zero sacc + mx + cnt + deg (contiguous region)
  hipMemsetAsync(ws + OFF_SACC, 0,
                 (size_t)NB * HD * 4 * 2 + 1024 + (size_t)NN * 4, stream);

  k_detect<<<1, 64, 0, stream>>>((const u16*)We, flag);
  k_prep<<<256, 256, 0, stream>>>(mW1, mW2, uW1, uW2, oW1, oW2, flag,
                                  Wt1, Wt2p, Wtu1, Wtu2p, Wto1, Wto2p);
  k_featinit<<<(NN * HD / 8) / 256, 256, 0, stream>>>(nemb, flag, feat);
  k_encode<<<NE / 256, 256, 0, stream>>>(d_d, We, be, flag, e);

  // CSR by dst (reused across layers)
  k_csr_deg<<<NE / 256, 256, 0, stream>>>(dst, deg);
  k_csr_scan<<<1, 1024, 0, stream>>>(deg, rowptr, cursor);
  k_csr_scatter<<<NE / 256, 256, 0, stream>>>(dst, cursor, eids);

  for (int l = 0; l < NL; l++) {
    k_edge<<<NE / 32, 64, 0, stream>>>(feat, e, src, dst, Wt1, Wt2p,
                                       mb1, mb2, sW, sb, flag, mbuf32, wgbuf, l);
    k_gather<<<NN / 4, 256, 0, stream>>>(rowptr, eids, mbuf32, wgbuf, msum);
    k_node<<<NN / 64, 64, 0, stream>>>(feat, msum, Wtu1, Wtu2p, ub1, ub2, flag, l);
  }
  k_out<<<NN / 64, 64, 0, stream>>>(feat, seg, Wto1, Wto2p, ob1, ob2, flag, sacc, mx, cnt);
  k_final<<<(NB * 384) / 256, 256, 0, stream>>>(sacc, mx, cnt, flag, d_out);
}

// Round 8
// 822.855 us; speedup vs baseline: 1.9347x; 1.3175x over previous
//
#include <hip/hip_runtime.h>

#define NN 32768   // nodes
#define NB 256     // graphs
#define HD 128     // hidden
#define NL 4       // layers
#define NE 262144  // edges

typedef short bf16x8 __attribute__((ext_vector_type(8)));
typedef float f32x4 __attribute__((ext_vector_type(4)));
typedef unsigned short u16;
typedef unsigned int u32;

__device__ __forceinline__ float bf2f(u16 u) {
  return __uint_as_float(((u32)u) << 16);
}
__device__ __forceinline__ u16 f2bf(float f) {
  u32 x = __float_as_uint(f);
  u32 r = x + 0x7FFFu + ((x >> 16) & 1u);
  return (u16)(r >> 16);
}
__device__ __forceinline__ u32 pk2(float a, float b) {
  return (u32)f2bf(a) | ((u32)f2bf(b) << 16);
}
__device__ __forceinline__ float siluf(float x) {
  return x * __builtin_amdgcn_rcpf(1.0f + __expf(-x));
}
__device__ __forceinline__ float sigf(float x) {
  return __builtin_amdgcn_rcpf(1.0f + __expf(-x));
}
__device__ __forceinline__ u32 ordu(float f) {
  u32 b = __float_as_uint(f);
  return (b & 0x80000000u) ? ~b : (b | 0x80000000u);
}

// ---- adaptive input loads: mode 1 = f32 inputs, mode 0 = bf16 inputs ----
__device__ __forceinline__ float ldinf(const void* p, size_t i, int mode) {
  return mode ? ((const float*)p)[i] : bf2f(((const u16*)p)[i]);
}
__device__ __forceinline__ u16 ldinb(const void* p, size_t i, int mode) {
  return mode ? f2bf(((const float*)p)[i]) : ((const u16*)p)[i];
}

// ---- dtype detector (confirmed mode=1/f32; kept as cheap guard) ----
__global__ void k_detect(const u16* __restrict__ Weraw, int* __restrict__ flag) {
  if (threadIdx.x == 0 && blockIdx.x == 0) {
    int cnt = 0;
    for (int i = 0; i < 256; i++) {
      u16 u = Weraw[2 * i];
      u32 e = (u >> 7) & 0xFFu;
      if (e >= 112u && e <= 126u) cnt++;
    }
    *flag = (cnt >= 128) ? 0 : 1;
  }
}

// ---------------- CSR build (by dst), reused across all 4 layers ----------------
__global__ __launch_bounds__(256) void k_csr_deg(const int* __restrict__ dstp,
                                                 u32* __restrict__ deg) {
  const int i = blockIdx.x * 256 + threadIdx.x;
  atomicAdd(&deg[dstp[i]], 1u);
}

__global__ __launch_bounds__(1024) void k_csr_scan(const u32* __restrict__ deg,
                                                   int* __restrict__ rowptr,
                                                   int* __restrict__ cursor) {
  __shared__ int part[1024];
  const int t = threadIdx.x;
  int loc[32];
  int s = 0;
#pragma unroll
  for (int j = 0; j < 32; j++) { loc[j] = s; s += (int)deg[t * 32 + j]; }
  part[t] = s;
  __syncthreads();
  int inc = s;
  for (int off = 1; off < 1024; off <<= 1) {
    int tmp = (t >= off) ? part[t - off] : 0;
    __syncthreads();
    part[t] += tmp;
    __syncthreads();
  }
  const int base = part[t] - inc;
#pragma unroll
  for (int j = 0; j < 32; j++) {
    rowptr[t * 32 + j] = base + loc[j];
    cursor[t * 32 + j] = base + loc[j];
  }
  if (t == 1023) rowptr[NN] = part[1023];
}

__global__ __launch_bounds__(256) void k_csr_scatter(const int* __restrict__ dstp,
                                                     int* __restrict__ cursor,
                                                     int* __restrict__ eids) {
  const int i = blockIdx.x * 256 + threadIdx.x;
  const int pos = atomicAdd(&cursor[dstp[i]], 1);
  eids[pos] = i;
}

// ---------------- per-wave GEMM pieces ----------------
// Wave tile: MT*16 rows x 128 cols, mfma_f32_16x16x32_bf16.
// A-frag: lane l holds A[row=(l&15)+16*mt][k=(l>>4)*8+j]  (16B contiguous)
// B PACKED layout (per 128x128 panel): Bp[((nt*4+ks)*64 + lane)*8 + j]
//   = W[k=ks*32+(lane>>4)*8+j][col=nt*16+(lane&15)]
//   => every b-load is one CONTIGUOUS 1KB segment across the wave.
// C/D: col = lane&15, row = (lane>>4)*4 + reg  (m89-verified)
// LDS tile: [rows][128 shorts], XOR-swizzled 16B granules (g ^= row&7).
// Packed k_new order: granule g element j <-> h = j*16 + g
//   => lane l's h=l value: short offset r*HD + ((l&15)^(r&7))*8 + (l>>4); h=l+64 at +4.
#define PANEL 16384  // shorts per packed 128x128 weight panel

template <int MT>
__device__ __forceinline__ void acc_zero(f32x4 (&acc)[MT][8]) {
#pragma unroll
  for (int mt = 0; mt < MT; mt++)
#pragma unroll
    for (int nt = 0; nt < 8; nt++) acc[mt][nt] = f32x4{0.f, 0.f, 0.f, 0.f};
}

// GEMM, A-frags direct from global rows, B from packed panel (coalesced 1KB).
template <int MT>
__device__ __forceinline__ void gemm_gp(const u16* __restrict__ A0,
                                        const size_t* rowoff,
                                        const u16* __restrict__ Bp,
                                        int l, int kg, f32x4 (&acc)[MT][8]) {
#pragma unroll
  for (int ks = 0; ks < 4; ks++) {
    bf16x8 a[MT];
#pragma unroll
    for (int mt = 0; mt < MT; mt++)
      a[mt] = *(const bf16x8*)&A0[rowoff[mt] + ks * 32 + kg * 8];
#pragma unroll
    for (int nt = 0; nt < 8; nt++) {
      bf16x8 b = *(const bf16x8*)&Bp[(size_t)((nt * 4 + ks) * 64 + l) * 8];
#pragma unroll
      for (int mt = 0; mt < MT; mt++)
        acc[mt][nt] = __builtin_amdgcn_mfma_f32_16x16x32_bf16(a[mt], b, acc[mt][nt], 0, 0, 0);
    }
  }
}

// GEMM, A from swizzled LDS tile, B from packed panel.
template <int MT>
__device__ __forceinline__ void wave_gemm_p(const short* lAw, const u16* __restrict__ Bp,
                                            int l, int c, int kg, f32x4 (&acc)[MT][8]) {
#pragma unroll
  for (int ks = 0; ks < 4; ks++) {
    bf16x8 a[MT];
#pragma unroll
    for (int mt = 0; mt < MT; mt++) {
      const int r = mt * 16 + c;
      const int k = ks * 32 + kg * 8;
      a[mt] = *(const bf16x8*)&lAw[r * HD + (k ^ ((r & 7) << 3))];
    }
#pragma unroll
    for (int nt = 0; nt < 8; nt++) {
      bf16x8 b = *(const bf16x8*)&Bp[(size_t)((nt * 4 + ks) * 64 + l) * 8];
#pragma unroll
      for (int mt = 0; mt < MT; mt++)
        acc[mt][nt] = __builtin_amdgcn_mfma_f32_16x16x32_bf16(a[mt], b, acc[mt][nt], 0, 0, 0);
    }
  }
}

template <int MT, bool SILU>
__device__ __forceinline__ void wave_pack(short* lAw, int c, int kg,
                                          f32x4 (&acc)[MT][8], const float* bias) {
#pragma unroll
  for (int mt = 0; mt < MT; mt++) {
#pragma unroll
    for (int rr = 0; rr < 4; rr++) {
      const int row = mt * 16 + kg * 4 + rr;
      u32 ou[4];
#pragma unroll
      for (int p = 0; p < 4; p++) {
        float x0 = acc[mt][2 * p][rr] + bias[2 * p];
        float x1 = acc[mt][2 * p + 1][rr] + bias[2 * p + 1];
        if (SILU) { x0 = siluf(x0); x1 = siluf(x1); }
        ou[p] = pk2(x0, x1);
      }
      ((int4*)(lAw + row * HD))[c ^ (row & 7)] =
          make_int4((int)ou[0], (int)ou[1], (int)ou[2], (int)ou[3]);
    }
  }
}

// ---------------- weight prep: pack into per-instruction fragment order -------
__global__ __launch_bounds__(256) void k_prep(
    const void* __restrict__ mW1, const void* __restrict__ mW2,
    const void* __restrict__ uW1, const void* __restrict__ uW2,
    const void* __restrict__ oW1, const void* __restrict__ oW2,
    const int* __restrict__ flagp,
    u16* __restrict__ Wt1, u16* __restrict__ Wt2p,
    u16* __restrict__ Wtu1, u16* __restrict__ Wtu2p,
    u16* __restrict__ Wto1, u16* __restrict__ Wto2p) {
  const int mode = *flagp;
  const int tid = blockIdx.x * blockDim.x + threadIdx.x;
  const int stride = gridDim.x * blockDim.x;
  // W1: [NL][3 chunks][PANEL], k = chunk*128 + ks*32 + (lane>>4)*8 + j
  for (int i = tid; i < NL * 3 * PANEL; i += stride) {
    const int l = i / (3 * PANEL), r = i % (3 * PANEL);
    const int chunk = r / PANEL, r2 = r % PANEL;
    const int nt = r2 / 2048, ks = (r2 % 2048) / 512;
    const int lane = (r2 % 512) / 8, j = r2 % 8;
    const int k = chunk * 128 + ks * 32 + (lane >> 4) * 8 + j;
    const int n = nt * 16 + (lane & 15);
    Wt1[i] = ldinb(mW1, ((size_t)l * 384 + k) * HD + n, mode);
  }
  // HDxHD panels: k = ks*32 + (lane>>4)*8 + j ; GEMM2-side fold perm(k)
  for (int i = tid; i < NL * PANEL; i += stride) {
    const int l = i / PANEL, r = i % PANEL;
    const int nt = r / 2048, ks = (r % 2048) / 512;
    const int lane = (r % 512) / 8, j = r % 8;
    const int k = ks * 32 + (lane >> 4) * 8 + j;
    const int n = nt * 16 + (lane & 15);
    const int hp = ((k & 7) << 4) | (k >> 3);
    Wt2p[i] = ldinb(mW2, ((size_t)l * HD + hp) * HD + n, mode);
    Wtu1[i] = ldinb(uW1, ((size_t)l * HD + k) * HD + n, mode);
    Wtu2p[i] = ldinb(uW2, ((size_t)l * HD + hp) * HD + n, mode);
  }
  for (int i = tid; i < PANEL; i += stride) {
    const int nt = i / 2048, ks = (i % 2048) / 512;
    const int lane = (i % 512) / 8, j = i % 8;
    const int k = ks * 32 + (lane >> 4) * 8 + j;
    const int n = nt * 16 + (lane & 15);
    const int hp = ((k & 7) << 4) | (k >> 3);
    Wto1[i] = ldinb(oW1, (size_t)k * HD + n, mode);
    Wto2p[i] = ldinb(oW2, (size_t)hp * HD + n, mode);
  }
}

// ---------------- feat init ----------------
__global__ __launch_bounds__(256) void k_featinit(const void* __restrict__ nemb,
                                                  const int* __restrict__ flagp,
                                                  u16* __restrict__ feat) {
  const int mode = *flagp;
  const int i = blockIdx.x * 256 + threadIdx.x;
  const int g = i & 15;
  u32 ou[4];
#pragma unroll
  for (int p = 0; p < 4; p++) {
    u16 a = ldinb(nemb, g * 8 + 2 * p, mode);
    u16 b = ldinb(nemb, g * 8 + 2 * p + 1, mode);
    ou[p] = (u32)a | ((u32)b << 16);
  }
  ((int4*)feat)[i] = make_int4((int)ou[0], (int)ou[1], (int)ou[2], (int)ou[3]);
}

// ---------------- edge feature encode ----------------
__global__ __launch_bounds__(256) void k_encode(const void* __restrict__ d,
                                                const void* __restrict__ We,
                                                const void* __restrict__ be,
                                                const int* __restrict__ flagp,
                                                u16* __restrict__ e) {
  const int mode = *flagp;
  __shared__ float sW[9 * HD];
  __shared__ float sb[HD];
  for (int i = threadIdx.x; i < 9 * HD; i += 256) sW[i] = ldinf(We, i, mode);
  for (int i = threadIdx.x; i < HD; i += 256) sb[i] = ldinf(be, i, mode);
  __syncthreads();
  const int eid = blockIdx.x * 256 + threadIdx.x;
  const float dv = ldinf(d, eid, mode);
  float de[9];
#pragma unroll
  for (int k = 0; k < 4; k++) {
    float x = dv * (1.0f / (float)(1 << k));
    de[k] = __sinf(x);
    de[4 + k] = __cosf(x);
  }
  de[8] = dv;
  u16* erow = e + (size_t)eid * HD;
#pragma unroll
  for (int hb = 0; hb < 16; hb++) {
    u32 ou[4];
#pragma unroll
    for (int p = 0; p < 4; p++) {
      float vv[2];
#pragma unroll
      for (int t = 0; t < 2; t++) {
        const int h = hb * 8 + 2 * p + t;
        float a = sb[h];
#pragma unroll
        for (int k = 0; k < 9; k++) a += de[k] * sW[k * HD + h];
        vv[t] = siluf(siluf(a));
      }
      ou[p] = pk2(vv[0], vv[1]);
    }
    ((int4*)erow)[hb] = make_int4((int)ou[0], (int)ou[1], (int)ou[2], (int)ou[3]);
  }
}

// ---------------- edge message layer: M=32 tiles, packed-B coalesced loads ----
__global__ __launch_bounds__(64, 4) void k_edge(
    const u16* __restrict__ feat, u16* __restrict__ e,
    const int* __restrict__ src, const int* __restrict__ dstp,
    const u16* __restrict__ Wt1, const u16* __restrict__ Wt2p,
    const void* __restrict__ b1g, const void* __restrict__ b2g,
    const void* __restrict__ softW, const void* __restrict__ softb,
    const int* __restrict__ flagp, u32* __restrict__ mbuf32,
    float* __restrict__ wgbuf, int layer) {
  __shared__ __align__(16) short lM[32 * HD];
  __shared__ float swg[32];
  const int mode = *flagp;
  const int l = threadIdx.x;
  const int c = l & 15, kg = l >> 4;
  const int blk = blockIdx.x * 32;

  size_t offS[2], offD[2], offE[2];
#pragma unroll
  for (int mt = 0; mt < 2; mt++) {
    const int eidx = blk + mt * 16 + c;
    offS[mt] = (size_t)src[eidx] * HD;
    offD[mt] = (size_t)dstp[eidx] * HD;
    offE[mt] = (size_t)eidx * HD;
  }

  const u16* W1l = Wt1 + (size_t)layer * 3 * PANEL;
  const u16* W2l = Wt2p + (size_t)layer * PANEL;
  float bias1[8], bias2[8], swf[8];
#pragma unroll
  for (int nt = 0; nt < 8; nt++) {
    bias1[nt] = ldinf(b1g, layer * HD + nt * 16 + c, mode);
    bias2[nt] = ldinf(b2g, layer * HD + nt * 16 + c, mode);
    swf[nt] = ldinf(softW, (size_t)layer * HD + nt * 16 + c, mode);
  }
  const float sbv = ldinf(softb, layer, mode);

  f32x4 acc[2][8];
  acc_zero<2>(acc);
  gemm_gp<2>(feat, offS, W1l, l, kg, acc);
  gemm_gp<2>(feat, offD, W1l + PANEL, l, kg, acc);
  gemm_gp<2>(e, offE, W1l + 2 * PANEL, l, kg, acc);
  wave_pack<2, true>(lM, c, kg, acc, bias1);   // h1, k_new order
  __syncthreads();

  acc_zero<2>(acc);
  wave_gemm_p<2>(lM, W2l, l, c, kg, acc);      // h1 @ W2 (perm folded in pack)
  __syncthreads();

  // ---- fused pack + soft-gate ----
  float wred[2][4];
#pragma unroll
  for (int mt = 0; mt < 2; mt++) {
#pragma unroll
    for (int rr = 0; rr < 4; rr++) {
      const int row = mt * 16 + kg * 4 + rr;
      float mv[8];
      float wp = 0.f;
#pragma unroll
      for (int nt = 0; nt < 8; nt++) {
        mv[nt] = siluf(acc[mt][nt][rr] + bias2[nt]);
        wp += mv[nt] * swf[nt];
      }
      u32 ou[4];
#pragma unroll
      for (int p = 0; p < 4; p++) ou[p] = pk2(mv[2 * p], mv[2 * p + 1]);
      ((int4*)(lM + row * HD))[c ^ (row & 7)] =
          make_int4((int)ou[0], (int)ou[1], (int)ou[2], (int)ou[3]);
      wp += __shfl_xor(wp, 1);
      wp += __shfl_xor(wp, 2);
      wp += __shfl_xor(wp, 4);
      wp += __shfl_xor(wp, 8);
      wred[mt][rr] = wp;
    }
  }
#pragma unroll
  for (int mt = 0; mt < 2; mt++)
#pragma unroll
    for (int rr = 0; rr < 4; rr++)
      if (c == mt * 4 + rr) swg[mt * 16 + kg * 4 + rr] = sigf(wred[mt][rr] + sbv);
  __syncthreads();

  if (l < 32) wgbuf[blk + l] = swg[l];

  // ---- cooperative per-row: mbuf store + e residual RMW ----
  const int j1 = l >> 4;
  const int goff = l & 15;
  const bool hilane = (l >= 32);
  const int s0 = (2 * l) & 63, s1 = (2 * l + 1) & 63;
#pragma unroll 4
  for (int r = 0; r < 32; r++) {
    const int base = r * HD + ((goff ^ (r & 7)) << 3) + j1;
    const u32 m1 = (u16)lM[base];        // h = l
    const u32 m2 = (u16)lM[base + 4];    // h = l + 64
    const u32 pk = m1 | (m2 << 16);
    const u32 a = (u32)__shfl((int)pk, s0);
    const u32 b = (u32)__shfl((int)pk, s1);
    const u32 lo = hilane ? (a >> 16) : (a & 0xffffu);
    const u32 hi = hilane ? (b >> 16) : (b & 0xffffu);
    mbuf32[(size_t)(blk + r) * 64 + l] = lo | (hi << 16);   // m at h=2l,2l+1
    u32* erow32 = (u32*)(e + (size_t)(blk + r) * HD);
    const u32 old = erow32[l];
    erow32[l] = pk2(bf2f((u16)(old & 0xffffu)) + bf2f((u16)lo),
                    bf2f((u16)(old >> 16)) + bf2f((u16)hi));
  }
}

// ---------------- msum gather: one wave per node ----------------
__global__ __launch_bounds__(256) void k_gather(
    const int* __restrict__ rowptr, const int* __restrict__ eids,
    const u32* __restrict__ mbuf32, const float* __restrict__ wgbuf,
    float* __restrict__ msum) {
  const int w = threadIdx.x >> 6;
  const int l = threadIdx.x & 63;
  const int node = blockIdx.x * 4 + w;
  const int beg = rowptr[node], end = rowptr[node + 1];
  float a0 = 0.f, a1 = 0.f;
  for (int cb = beg; cb < end; cb += 64) {
    int eL = 0;
    float wL = 0.f;
    if (cb + l < end) { eL = eids[cb + l]; wL = wgbuf[eL]; }
    const int nj = min(64, end - cb);
    for (int j = 0; j < nj; j++) {
      const int eid = __shfl(eL, j);
      const float wj = __shfl(wL, j);
      const u32 v = mbuf32[(size_t)eid * 64 + l];
      a0 += wj * bf2f((u16)(v & 0xffffu));
      a1 += wj * bf2f((u16)(v >> 16));
    }
  }
  ((float2*)(msum + (size_t)node * HD))[l] = make_float2(a0, a1);  // h=2l,2l+1
}

// ---------------- node update layer ----------------
__global__ __launch_bounds__(64, 2) void k_node(
    u16* __restrict__ feat, const float* __restrict__ msum,
    const u16* __restrict__ Wtu1, const u16* __restrict__ Wtu2p,
    const void* __restrict__ b1g, const void* __restrict__ b2g,
    const int* __restrict__ flagp, int layer) {
  __shared__ __align__(16) short lA[64 * HD];
  const int mode = *flagp;
  const int l = threadIdx.x;
  const int c = l & 15, kg = l >> 4;
  short* lAw = lA;
  const int blkn = blockIdx.x * 64;
  const int myrow = blkn + l;
  u16* frow = feat + (size_t)myrow * HD;
  const float* mrow = msum + (size_t)myrow * HD;
  const u16* W1l = Wtu1 + (size_t)layer * PANEL;
  const u16* W2l = Wtu2p + (size_t)layer * PANEL;
  float bias1[8], bias2[8];
#pragma unroll
  for (int nt = 0; nt < 8; nt++) {
    bias1[nt] = ldinf(b1g, layer * HD + nt * 16 + c, mode);
    bias2[nt] = ldinf(b2g, layer * HD + nt * 16 + c, mode);
  }
  {
    int4* lrow = (int4*)(lAw + l * HD);
#pragma unroll
    for (int g = 0; g < 16; g++) {
      int4 fv = ((const int4*)frow)[g];
      u32 uu[4] = {(u32)fv.x, (u32)fv.y, (u32)fv.z, (u32)fv.w};
      float4 ma = ((const float4*)mrow)[2 * g];
      float4 mb = ((const float4*)mrow)[2 * g + 1];
      float mm[8] = {ma.x, ma.y, ma.z, ma.w, mb.x, mb.y, mb.z, mb.w};
      u32 ou[4];
#pragma unroll
      for (int p = 0; p < 4; p++) {
        float a0 = bf2f((u16)(uu[p] & 0xffffu)) + mm[2 * p];
        float a1 = bf2f((u16)(uu[p] >> 16)) + mm[2 * p + 1];
        ou[p] = pk2(a0, a1);
      }
      lrow[g ^ (l & 7)] = make_int4((int)ou[0], (int)ou[1], (int)ou[2], (int)ou[3]);
    }
  }
  __syncthreads();
  f32x4 acc[4][8];
  acc_zero<4>(acc);
  wave_gemm_p<4>(lAw, W1l, l, c, kg, acc);
  __syncthreads();
  wave_pack<4, true>(lAw, c, kg, acc, bias1);
  __syncthreads();
  acc_zero<4>(acc);
  wave_gemm_p<4>(lAw, W2l, l, c, kg, acc);
  __syncthreads();
  wave_pack<4, false>(lAw, c, kg, acc, bias2);
  __syncthreads();

  // cooperative feat residual: coalesced u32 RMW per row
  const int j1 = l >> 4;
  const int goff = l & 15;
  const bool hilane = (l >= 32);
  const int s0 = (2 * l) & 63, s1 = (2 * l + 1) & 63;
#pragma unroll 4
  for (int r = 0; r < 64; r++) {
    const int base = r * HD + ((goff ^ (r & 7)) << 3) + j1;
    const u32 m1 = (u16)lAw[base];
    const u32 m2 = (u16)lAw[base + 4];
    const u32 pk = m1 | (m2 << 16);
    const u32 a = (u32)__shfl((int)pk, s0);
    const u32 b = (u32)__shfl((int)pk, s1);
    const u32 lo = hilane ? (a >> 16) : (a & 0xffffu);
    const u32 hi = hilane ? (b >> 16) : (b & 0xffffu);
    u32* frow32 = (u32*)(feat + (size_t)(blkn + r) * HD);
    const u32 old = frow32[l];
    frow32[l] = pk2(bf2f((u16)(old & 0xffffu)) + bf2f((u16)lo),
                    bf2f((u16)(old >> 16)) + bf2f((u16)hi));
  }
}

// ---------------- output MLP + readout ----------------
__global__ __launch_bounds__(64, 2) void k_out(
    const u16* __restrict__ feat, const int* __restrict__ seg,
    const u16* __restrict__ Wto1, const u16* __restrict__ Wto2p,
    const void* __restrict__ ob1, const void* __restrict__ ob2,
    const int* __restrict__ flagp,
    float* __restrict__ sacc, u32* __restrict__ mxacc, float* __restrict__ cnt) {
  __shared__ __align__(16) short lA[64 * HD];
  __shared__ int sseg[64];
  const int mode = *flagp;
  const int l = threadIdx.x;
  const int c = l & 15, kg = l >> 4;
  short* lAw = lA;
  const int myrow = blockIdx.x * 64 + l;
  const u16* frow = feat + (size_t)myrow * HD;
  float bias1[8], bias2[8];
#pragma unroll
  for (int nt = 0; nt < 8; nt++) {
    bias1[nt] = ldinf(ob1, nt * 16 + c, mode);
    bias2[nt] = ldinf(ob2, nt * 16 + c, mode);
  }
  {
    int4* lrow = (int4*)(lAw + l * HD);
#pragma unroll
    for (int g = 0; g < 16; g++) lrow[g ^ (l & 7)] = ((const int4*)frow)[g];
  }
  sseg[l] = seg[myrow];
  __syncthreads();
  f32x4 acc[4][8];
  acc_zero<4>(acc);
  wave_gemm_p<4>(lAw, Wto1, l, c, kg, acc);
  __syncthreads();
  wave_pack<4, true>(lAw, c, kg, acc, bias1);
  __syncthreads();
  acc_zero<4>(acc);
  wave_gemm_p<4>(lAw, Wto2p, l, c, kg, acc);
  __syncthreads();
  wave_pack<4, false>(lAw, c, kg, acc, bias2);
  __syncthreads();

  const int j1 = l >> 4;
  const int goff = l & 15;
  const bool uniform = (sseg[0] == sseg[63]);
  if (uniform) {
    const int g = sseg[0];
    float s1 = 0.f, s2 = 0.f, x1 = -3.402823e38f, x2 = -3.402823e38f;
#pragma unroll 4
    for (int r = 0; r < 64; r++) {
      const int base = r * HD + ((goff ^ (r & 7)) << 3) + j1;
      const float v1 = bf2f((u16)lAw[base]);
      const float v2 = bf2f((u16)lAw[base + 4]);
      s1 += v1; s2 += v2;
      x1 = fmaxf(x1, v1); x2 = fmaxf(x2, v2);
    }
    atomicAdd(&sacc[(size_t)g * HD + l], s1);
    atomicAdd(&sacc[(size_t)g * HD + l + 64], s2);
    atomicMax(&mxacc[(size_t)g * HD + l], ordu(x1));
    atomicMax(&mxacc[(size_t)g * HD + l + 64], ordu(x2));
    if (l == 0) atomicAdd(&cnt[g], 64.0f);
  } else {
    atomicAdd(&cnt[sseg[l]], 1.0f);
#pragma unroll 4
    for (int r = 0; r < 64; r++) {
      const int base = r * HD + ((goff ^ (r & 7)) << 3) + j1;
      const float v1 = bf2f((u16)lAw[base]);
      const float v2 = bf2f((u16)lAw[base + 4]);
      const int g = sseg[r];
      atomicAdd(&sacc[(size_t)g * HD + l], v1);
      atomicAdd(&sacc[(size_t)g * HD + l + 64], v2);
      atomicMax(&mxacc[(size_t)g * HD + l], ordu(v1));
      atomicMax(&mxacc[(size_t)g * HD + l + 64], ordu(v2));
    }
  }
}

// ---------------- finalize ----------------
__global__ __launch_bounds__(256) void k_final(const float* __restrict__ sacc,
                                               const u32* __restrict__ mxacc,
                                               const float* __restrict__ cnt,
                                               const int* __restrict__ flagp,
                                               void* __restrict__ out) {
  const int mode = *flagp;
  const int i = blockIdx.x * 256 + threadIdx.x;
  const int b = i / 384, j = i % 384;
  float v;
  if (j < HD) v = sacc[b * HD + j];
  else if (j < 2 * HD) v = sacc[b * HD + (j - HD)] / fmaxf(cnt[b], 1.0f);
  else {
    u32 u = mxacc[b * HD + (j - 2 * HD)];
    u32 bits = (u >> 31) ? (u ^ 0x80000000u) : ~u;
    v = __uint_as_float(bits);
  }
  if (mode) ((float*)out)[i] = v;
  else ((u16*)out)[i] = f2bf(v);
}

extern "C" void kernel_launch(void* const* d_in, const int* in_sizes, int n_in,
                              void* d_out, int out_size, void* d_ws, size_t ws_size,
                              hipStream_t stream) {
  const void* d_d = d_in[0];
  const int* src = (const int*)d_in[1];
  const int* dst = (const int*)d_in[2];
  const int* seg = (const int*)d_in[3];
  const void* nemb = d_in[4];
  const void* We = d_in[5];
  const void* be = d_in[6];
  const void* mW1 = d_in[7];
  const void* mb1 = d_in[8];
  const void* mW2 = d_in[9];
  const void* mb2 = d_in[10];
  const void* sW = d_in[11];
  const void* sb = d_in[12];
  const void* uW1 = d_in[13];
  const void* ub1 = d_in[14];
  const void* uW2 = d_in[15];
  const void* ub2 = d_in[16];
  const void* oW1 = d_in[17];
  const void* ob1 = d_in[18];
  const void* oW2 = d_in[19];
  const void* ob2 = d_in[20];

  char* ws = (char*)d_ws;
  const size_t OFF_E = 0;
  const size_t OFF_MBUF = OFF_E + (size_t)NE * HD * 2;
  const size_t OFF_WG = OFF_MBUF + (size_t)NE * HD * 2;
  const size_t OFF_MSUM = OFF_WG + (size_t)NE * 4;
  const size_t OFF_FEAT = OFF_MSUM + (size_t)NN * HD * 4;
  const size_t OFF_SACC = OFF_FEAT + (size_t)NN * HD * 2;
  const size_t OFF_MX = OFF_SACC + (size_t)NB * HD * 4;
  const size_t OFF_CNT = OFF_MX + (size_t)NB * HD * 4;
  const size_t OFF_DEG = OFF_CNT + 1024;
  const size_t OFF_ROWPTR = OFF_DEG + (size_t)NN * 4;
  const size_t OFF_CURSOR = OFF_ROWPTR + (size_t)(NN + 2) * 4;
  const size_t OFF_EIDS = OFF_CURSOR + (size_t)NN * 4;
  const size_t OFF_WT1 = OFF_EIDS + (size_t)NE * 4;
  const size_t OFF_WT2P = OFF_WT1 + (size_t)NL * 3 * PANEL * 2;
  const size_t OFF_WTU1 = OFF_WT2P + (size_t)NL * PANEL * 2;
  const size_t OFF_WTU2P = OFF_WTU1 + (size_t)NL * PANEL * 2;
  const size_t OFF_WTO1 = OFF_WTU2P + (size_t)NL * PANEL * 2;
  const size_t OFF_WTO2P = OFF_WTO1 + (size_t)PANEL * 2;
  const size_t OFF_FLAG = OFF_WTO2P + (size_t)PANEL * 2;

  u16* e = (u16*)(ws + OFF_E);
  u32* mbuf32 = (u32*)(ws + OFF_MBUF);
  float* wgbuf = (float*)(ws + OFF_WG);
  float* msum = (float*)(ws + OFF_MSUM);
  u16* feat = (u16*)(ws + OFF_FEAT);
  float* sacc = (float*)(ws + OFF_SACC);
  u32* mx = (u32*)(ws + OFF_MX);
  float* cnt = (float*)(ws + OFF_CNT);
  u32* deg = (u32*)(ws + OFF_DEG);
  int* rowptr = (int*)(ws + OFF_ROWPTR);
  int* cursor = (int*)(ws + OFF_CURSOR);
  int* eids = (int*)(ws + OFF_EIDS);
  u16* Wt1 = (u16*)(ws + OFF_WT1);
  u16* Wt2p = (u16*)(ws + OFF_WT2P);
  u16* Wtu1 = (u16*)(ws + OFF_WTU1);
  u16* Wtu2p = (u16*)(ws + OFF_WTU2P);
  u16* Wto1 = (u16*)(ws + OFF_WTO1);
  u16* Wto2p = (u16*)(ws + OFF_WTO2P);
  int* flag = (int*)(ws + OFF_FLAG);

  // zero sacc + mx + cnt + deg (contiguous region)
  hipMemsetAsync(ws + OFF_SACC, 0,
                 (size_t)NB * HD * 4 * 2 + 1024 + (size_t)NN * 4, stream);

  k_detect<<<1, 64, 0, stream>>>((const u16*)We, flag);
  k_prep<<<256, 256, 0, stream>>>(mW1, mW2, uW1, uW2, oW1, oW2, flag,
                                  Wt1, Wt2p, Wtu1, Wtu2p, Wto1, Wto2p);
  k_featinit<<<(NN * HD / 8) / 256, 256, 0, stream>>>(nemb, flag, feat);
  k_encode<<<NE / 256, 256, 0, stream>>>(d_d, We, be, flag, e);

  // CSR by dst (reused across layers)
  k_csr_deg<<<NE / 256, 256, 0, stream>>>(dst, deg);
  k_csr_scan<<<1, 1024, 0, stream>>>(deg, rowptr, cursor);
  k_csr_scatter<<<NE / 256, 256, 0, stream>>>(dst, cursor, eids);

  for (int l = 0; l < NL; l++) {
    k_edge<<<NE / 32, 64, 0, stream>>>(feat, e, src, dst, Wt1, Wt2p,
                                       mb1, mb2, sW, sb, flag, mbuf32, wgbuf, l);
    k_gather<<<NN / 4, 256, 0, stream>>>(rowptr, eids, mbuf32, wgbuf, msum);
    k_node<<<NN / 64, 64, 0, stream>>>(feat, msum, Wtu1, Wtu2p, ub1, ub2, flag, l);
  }
  k_out<<<NN / 64, 64, 0, stream>>>(feat, seg, Wto1, Wto2p, ob1, ob2, flag, sacc, mx, cnt);
  k_final<<<(NB * 384) / 256, 256, 0, stream>>>(sacc, mx, cnt, flag, d_out);
}